// Round 1
// baseline (652.641 us; speedup 1.0000x reference)
//
#include <hip/hip_runtime.h>
#include <math.h>

#define D_INNER 2048
#define DT_RANK 128
#define D_STATE 16
#define SEQ_B 2
#define SEQ_L 1024
#define M_ROWS (SEQ_B*SEQ_L)            // 2048
#define NCAT (DT_RANK + 2*D_STATE)      // 160

// ---------------- concat W_delta|W_B|W_C -> Wcat [2048][160] ----------------
__global__ void concat_w(const float* __restrict__ Wd, const float* __restrict__ Wb,
                         const float* __restrict__ Wc, float* __restrict__ Wcat) {
    int i = blockIdx.x * 256 + threadIdx.x;
    if (i >= D_INNER * NCAT) return;
    int k = i / NCAT, j = i % NCAT;
    float v;
    if (j < DT_RANK)                 v = Wd[k * DT_RANK + j];
    else if (j < DT_RANK + D_STATE)  v = Wb[k * D_STATE + (j - DT_RANK)];
    else                             v = Wc[k * D_STATE + (j - DT_RANK - D_STATE)];
    Wcat[i] = v;
}

// ---------------- generic 64x64 f32 tiled GEMM, optional softplus epilogue ---
template<bool SOFTPLUS>
__global__ __launch_bounds__(256)
void gemm_tile(const float* __restrict__ A, int lda,
               const float* __restrict__ B, int ldb,
               float* __restrict__ C, int ldc,
               int N, int K, const float* __restrict__ bias)
{
    __shared__ __align__(16) float As[16][64];
    __shared__ __align__(16) float Bs[16][64];
    const int tid = threadIdx.x;
    const int tx = tid & 15, ty = tid >> 4;
    const int row0 = blockIdx.y * 64;
    const int col0 = blockIdx.x * 64;

    float acc[4][4] = {};

    for (int k0 = 0; k0 < K; k0 += 16) {
        // A tile: 64 rows x 16 k.  lane pattern: 16 consecutive k per row.
        #pragma unroll
        for (int p = 0; p < 4; ++p) {
            int m = (tid >> 4) + p * 16;
            int k = tid & 15;
            As[k][m] = A[(size_t)(row0 + m) * lda + k0 + k];
        }
        // B tile: 16 k x 64 n. coalesced across n.
        #pragma unroll
        for (int p = 0; p < 4; ++p) {
            int k = (tid >> 6) + p * 4;
            int n = tid & 63;
            int col = col0 + n;
            Bs[k][n] = (col < N) ? B[(size_t)(k0 + k) * ldb + col] : 0.f;
        }
        __syncthreads();
        #pragma unroll
        for (int k = 0; k < 16; ++k) {
            float4 av = *(const float4*)&As[k][ty * 4];
            float4 bv = *(const float4*)&Bs[k][tx * 4];
            acc[0][0] += av.x * bv.x; acc[0][1] += av.x * bv.y; acc[0][2] += av.x * bv.z; acc[0][3] += av.x * bv.w;
            acc[1][0] += av.y * bv.x; acc[1][1] += av.y * bv.y; acc[1][2] += av.y * bv.z; acc[1][3] += av.y * bv.w;
            acc[2][0] += av.z * bv.x; acc[2][1] += av.z * bv.y; acc[2][2] += av.z * bv.z; acc[2][3] += av.z * bv.w;
            acc[3][0] += av.w * bv.x; acc[3][1] += av.w * bv.y; acc[3][2] += av.w * bv.z; acc[3][3] += av.w * bv.w;
        }
        __syncthreads();
    }

    #pragma unroll
    for (int i = 0; i < 4; ++i) {
        int row = row0 + ty * 4 + i;
        #pragma unroll
        for (int j = 0; j < 4; ++j) {
            int col = col0 + tx * 4 + j;
            if (col < N) {
                float v = acc[i][j];
                if (SOFTPLUS) {
                    v += bias[col];
                    v = (v > 20.f) ? v : log1pf(expf(v));
                }
                C[(size_t)row * ldc + col] = v;
            }
        }
    }
}

// ---------------- fused discretize + scan + output -------------------------
// one thread per (b, d, n); 16-lane groups reduce over n with shfl_xor.
__global__ __launch_bounds__(256)
void scan_kernel(const float* __restrict__ x, const float* __restrict__ P,
                 const float* __restrict__ delta, const float* __restrict__ A_log,
                 const float* __restrict__ Dp, float* __restrict__ y)
{
    int g = blockIdx.x * 256 + threadIdx.x;
    int n = g & (D_STATE - 1);
    int d = (g >> 4) & (D_INNER - 1);
    int b = g >> 15;

    float Adn = -expf(A_log[d * D_STATE + n]);
    float Dd  = Dp[d];

    const float* __restrict__ xrow = x     + (size_t)b * SEQ_L * D_INNER + d;
    const float* __restrict__ drow = delta + (size_t)b * SEQ_L * D_INNER + d;
    const float* __restrict__ prow = P     + (size_t)b * SEQ_L * NCAT;
    float* __restrict__ yrow       = y     + (size_t)b * SEQ_L * D_INNER + d;

    float h = 0.f;
    #pragma unroll 4
    for (int t = 0; t < SEQ_L; ++t) {
        float dt = drow[(size_t)t * D_INNER];
        float xt = xrow[(size_t)t * D_INNER];
        float Bt = prow[t * NCAT + DT_RANK + n];
        float Ct = prow[t * NCAT + DT_RANK + D_STATE + n];
        float a  = __expf(dt * Adn);
        h = a * h + dt * Bt * xt;
        float c = h * Ct;
        c += __shfl_xor(c, 1);
        c += __shfl_xor(c, 2);
        c += __shfl_xor(c, 4);
        c += __shfl_xor(c, 8);
        if (n == 0) yrow[(size_t)t * D_INNER] = c + xt * Dd;
    }
}

extern "C" void kernel_launch(void* const* d_in, const int* in_sizes, int n_in,
                              void* d_out, int out_size, void* d_ws, size_t ws_size,
                              hipStream_t stream) {
    const float* x       = (const float*)d_in[0];
    const float* W_delta = (const float*)d_in[1];
    const float* W_dt    = (const float*)d_in[2];
    const float* b_dt    = (const float*)d_in[3];
    const float* W_B     = (const float*)d_in[4];
    const float* W_C     = (const float*)d_in[5];
    const float* A_log   = (const float*)d_in[6];
    const float* Dp      = (const float*)d_in[7];
    float* y = (float*)d_out;

    char* ws = (char*)d_ws;
    float* Wcat  = (float*)(ws);                       // 2048*160*4 = 1310720 B
    float* P     = (float*)(ws + 1310720);             // 2048*160*4 = 1310720 B
    float* delta = (float*)(ws + 2621440);             // 2048*2048*4 = 16777216 B

    // 1) concat projection weights
    concat_w<<<dim3((D_INNER * NCAT + 255) / 256), 256, 0, stream>>>(W_delta, W_B, W_C, Wcat);
    // 2) P = x @ Wcat   [2048 x 160]
    gemm_tile<false><<<dim3(3, M_ROWS / 64), 256, 0, stream>>>(
        x, D_INNER, Wcat, NCAT, P, NCAT, NCAT, D_INNER, nullptr);
    // 3) delta = softplus(P[:, :128] @ W_dt + b_dt)   [2048 x 2048]
    gemm_tile<true><<<dim3(D_INNER / 64, M_ROWS / 64), 256, 0, stream>>>(
        P, NCAT, W_dt, D_INNER, delta, D_INNER, D_INNER, DT_RANK, b_dt);
    // 4) fused scan + output
    scan_kernel<<<dim3((SEQ_B * D_INNER * D_STATE) / 256), 256, 0, stream>>>(
        x, P, delta, A_log, Dp, y);
}

// Round 2
// 274.315 us; speedup vs baseline: 2.3792x; 2.3792x over previous
//
#include <hip/hip_runtime.h>
#include <math.h>

#define D_INNER 2048
#define DT_RANK 128
#define D_STATE 16
#define SEQ_B 2
#define SEQ_L 1024
#define M_ROWS (SEQ_B*SEQ_L)            // 2048
#define NCAT (DT_RANK + 2*D_STATE)      // 160
#define NC 32                           // scan chunks
#define LC (SEQ_L/NC)                   // 32 timesteps per chunk

// ---------------- concat W_delta|W_B|W_C -> Wcat [2048][160] ----------------
__global__ void concat_w(const float* __restrict__ Wd, const float* __restrict__ Wb,
                         const float* __restrict__ Wc, float* __restrict__ Wcat) {
    int i = blockIdx.x * 256 + threadIdx.x;
    if (i >= D_INNER * NCAT) return;
    int k = i / NCAT, j = i % NCAT;
    float v;
    if (j < DT_RANK)                 v = Wd[k * DT_RANK + j];
    else if (j < DT_RANK + D_STATE)  v = Wb[k * D_STATE + (j - DT_RANK)];
    else                             v = Wc[k * D_STATE + (j - DT_RANK - D_STATE)];
    Wcat[i] = v;
}

// ---------------- generic 64x64 f32 tiled GEMM, optional softplus epilogue ---
template<bool SOFTPLUS>
__global__ __launch_bounds__(256)
void gemm_tile(const float* __restrict__ A, int lda,
               const float* __restrict__ B, int ldb,
               float* __restrict__ C, int ldc,
               int N, int K, const float* __restrict__ bias)
{
    __shared__ __align__(16) float As[16][64];
    __shared__ __align__(16) float Bs[16][64];
    const int tid = threadIdx.x;
    const int tx = tid & 15, ty = tid >> 4;
    const int row0 = blockIdx.y * 64;
    const int col0 = blockIdx.x * 64;

    float acc[4][4] = {};

    for (int k0 = 0; k0 < K; k0 += 16) {
        #pragma unroll
        for (int p = 0; p < 4; ++p) {
            int m = (tid >> 4) + p * 16;
            int k = tid & 15;
            As[k][m] = A[(size_t)(row0 + m) * lda + k0 + k];
        }
        #pragma unroll
        for (int p = 0; p < 4; ++p) {
            int k = (tid >> 6) + p * 4;
            int n = tid & 63;
            int col = col0 + n;
            Bs[k][n] = (col < N) ? B[(size_t)(k0 + k) * ldb + col] : 0.f;
        }
        __syncthreads();
        #pragma unroll
        for (int k = 0; k < 16; ++k) {
            float4 av = *(const float4*)&As[k][ty * 4];
            float4 bv = *(const float4*)&Bs[k][tx * 4];
            acc[0][0] += av.x * bv.x; acc[0][1] += av.x * bv.y; acc[0][2] += av.x * bv.z; acc[0][3] += av.x * bv.w;
            acc[1][0] += av.y * bv.x; acc[1][1] += av.y * bv.y; acc[1][2] += av.y * bv.z; acc[1][3] += av.y * bv.w;
            acc[2][0] += av.z * bv.x; acc[2][1] += av.z * bv.y; acc[2][2] += av.z * bv.z; acc[2][3] += av.z * bv.w;
            acc[3][0] += av.w * bv.x; acc[3][1] += av.w * bv.y; acc[3][2] += av.w * bv.z; acc[3][3] += av.w * bv.w;
        }
        __syncthreads();
    }

    #pragma unroll
    for (int i = 0; i < 4; ++i) {
        int row = row0 + ty * 4 + i;
        #pragma unroll
        for (int j = 0; j < 4; ++j) {
            int col = col0 + tx * 4 + j;
            if (col < N) {
                float v = acc[i][j];
                if (SOFTPLUS) {
                    v += bias[col];
                    v = (v > 20.f) ? v : log1pf(expf(v));
                }
                C[(size_t)row * ldc + col] = v;
            }
        }
    }
}

// ---------------- chunked scan: pass 1 (local scan, h0 = 0) ----------------
// thread = (b, chunk c, d); 16 n-states in registers.
__global__ __launch_bounds__(256)
void scan_pass1(const float* __restrict__ x, const float* __restrict__ P,
                const float* __restrict__ delta, const float* __restrict__ A_log,
                float* __restrict__ chunkA, float* __restrict__ chunkH)
{
    const int d = blockIdx.x * 256 + threadIdx.x;
    const int c = blockIdx.y;
    const int b = blockIdx.z;
    const int t0 = c * LC;

    float Adn[D_STATE];
    #pragma unroll
    for (int n = 0; n < D_STATE; ++n) Adn[n] = -__expf(A_log[d * D_STATE + n]);

    float pA[D_STATE], h[D_STATE];
    #pragma unroll
    for (int n = 0; n < D_STATE; ++n) { pA[n] = 1.f; h[n] = 0.f; }

    const float* __restrict__ drow = delta + ((size_t)b * SEQ_L + t0) * D_INNER + d;
    const float* __restrict__ xrow = x     + ((size_t)b * SEQ_L + t0) * D_INNER + d;
    const float* __restrict__ prow = P     + ((size_t)b * SEQ_L + t0) * NCAT;

    for (int t = 0; t < LC; ++t) {
        float dt  = drow[(size_t)t * D_INNER];
        float xt  = xrow[(size_t)t * D_INNER];
        float dtx = dt * xt;
        const float4* Br = (const float4*)(prow + t * NCAT + DT_RANK);
        float4 b0 = Br[0], b1 = Br[1], b2 = Br[2], b3 = Br[3];
        float Bv[D_STATE] = {b0.x,b0.y,b0.z,b0.w, b1.x,b1.y,b1.z,b1.w,
                             b2.x,b2.y,b2.z,b2.w, b3.x,b3.y,b3.z,b3.w};
        #pragma unroll
        for (int n = 0; n < D_STATE; ++n) {
            float a = __expf(dt * Adn[n]);
            h[n]  = fmaf(a, h[n], dtx * Bv[n]);
            pA[n] *= a;
        }
    }
    size_t idx = (((size_t)b * D_INNER + d) * NC + c) * D_STATE;
    #pragma unroll
    for (int n = 0; n < D_STATE; ++n) { chunkA[idx + n] = pA[n]; chunkH[idx + n] = h[n]; }
}

// ---------------- pass 2: sequential fixup over NC chunks ------------------
// thread per (b,d,n): exclusive scan; chunkH is overwritten with each chunk's h0.
__global__ __launch_bounds__(256)
void scan_fixup(const float* __restrict__ chunkA, float* __restrict__ chunkH)
{
    int g = blockIdx.x * 256 + threadIdx.x;           // B*D*16 = 65536
    int n = g & (D_STATE - 1);
    int d = (g >> 4) & (D_INNER - 1);
    int b = g >> 15;
    size_t base = ((size_t)b * D_INNER + d) * NC * D_STATE + n;
    float h = 0.f;
    for (int c = 0; c < NC; ++c) {
        size_t idx = base + (size_t)c * D_STATE;
        float a  = chunkA[idx];
        float hl = chunkH[idx];
        chunkH[idx] = h;                               // h0 for chunk c
        h = fmaf(a, h, hl);
    }
}

// ---------------- pass 3: re-run chunk from true h0, emit y ----------------
__global__ __launch_bounds__(256)
void scan_pass3(const float* __restrict__ x, const float* __restrict__ P,
                const float* __restrict__ delta, const float* __restrict__ A_log,
                const float* __restrict__ Dp, const float* __restrict__ chunkH,
                float* __restrict__ y)
{
    const int d = blockIdx.x * 256 + threadIdx.x;
    const int c = blockIdx.y;
    const int b = blockIdx.z;
    const int t0 = c * LC;

    float Adn[D_STATE];
    #pragma unroll
    for (int n = 0; n < D_STATE; ++n) Adn[n] = -__expf(A_log[d * D_STATE + n]);
    float Dd = Dp[d];

    float h[D_STATE];
    {
        size_t idx = (((size_t)b * D_INNER + d) * NC + c) * D_STATE;
        const float4* H = (const float4*)(chunkH + idx);
        float4 h0 = H[0], h1 = H[1], h2 = H[2], h3 = H[3];
        h[0]=h0.x; h[1]=h0.y; h[2]=h0.z; h[3]=h0.w;
        h[4]=h1.x; h[5]=h1.y; h[6]=h1.z; h[7]=h1.w;
        h[8]=h2.x; h[9]=h2.y; h[10]=h2.z; h[11]=h2.w;
        h[12]=h3.x; h[13]=h3.y; h[14]=h3.z; h[15]=h3.w;
    }

    const float* __restrict__ drow = delta + ((size_t)b * SEQ_L + t0) * D_INNER + d;
    const float* __restrict__ xrow = x     + ((size_t)b * SEQ_L + t0) * D_INNER + d;
    const float* __restrict__ prow = P     + ((size_t)b * SEQ_L + t0) * NCAT;
    float* __restrict__ yrow       = y     + ((size_t)b * SEQ_L + t0) * D_INNER + d;

    for (int t = 0; t < LC; ++t) {
        float dt  = drow[(size_t)t * D_INNER];
        float xt  = xrow[(size_t)t * D_INNER];
        float dtx = dt * xt;
        const float4* Br = (const float4*)(prow + t * NCAT + DT_RANK);
        float4 b0 = Br[0], b1 = Br[1], b2 = Br[2], b3 = Br[3];
        float Bv[D_STATE] = {b0.x,b0.y,b0.z,b0.w, b1.x,b1.y,b1.z,b1.w,
                             b2.x,b2.y,b2.z,b2.w, b3.x,b3.y,b3.z,b3.w};
        const float4* Cr = (const float4*)(prow + t * NCAT + DT_RANK + D_STATE);
        float4 c0 = Cr[0], c1 = Cr[1], c2 = Cr[2], c3 = Cr[3];
        float Cv[D_STATE] = {c0.x,c0.y,c0.z,c0.w, c1.x,c1.y,c1.z,c1.w,
                             c2.x,c2.y,c2.z,c2.w, c3.x,c3.y,c3.z,c3.w};
        float acc = xt * Dd;
        #pragma unroll
        for (int n = 0; n < D_STATE; ++n) {
            float a = __expf(dt * Adn[n]);
            h[n] = fmaf(a, h[n], dtx * Bv[n]);
            acc  = fmaf(h[n], Cv[n], acc);
        }
        yrow[(size_t)t * D_INNER] = acc;
    }
}

extern "C" void kernel_launch(void* const* d_in, const int* in_sizes, int n_in,
                              void* d_out, int out_size, void* d_ws, size_t ws_size,
                              hipStream_t stream) {
    const float* x       = (const float*)d_in[0];
    const float* W_delta = (const float*)d_in[1];
    const float* W_dt    = (const float*)d_in[2];
    const float* b_dt    = (const float*)d_in[3];
    const float* W_B     = (const float*)d_in[4];
    const float* W_C     = (const float*)d_in[5];
    const float* A_log   = (const float*)d_in[6];
    const float* Dp      = (const float*)d_in[7];
    float* y = (float*)d_out;

    char* ws = (char*)d_ws;
    float* Wcat   = (float*)(ws);                      // 1,310,720 B
    float* P      = (float*)(ws + 1310720);            // 1,310,720 B
    float* delta  = (float*)(ws + 2621440);            // 16,777,216 B
    float* chunkA = (float*)(ws + 19398656);           // 8,388,608 B
    float* chunkH = (float*)(ws + 27787264);           // 8,388,608 B  -> total ~36.2 MB

    // 1) concat projection weights
    concat_w<<<dim3((D_INNER * NCAT + 255) / 256), 256, 0, stream>>>(W_delta, W_B, W_C, Wcat);
    // 2) P = x @ Wcat   [2048 x 160]
    gemm_tile<false><<<dim3(3, M_ROWS / 64), 256, 0, stream>>>(
        x, D_INNER, Wcat, NCAT, P, NCAT, NCAT, D_INNER, nullptr);
    // 3) delta = softplus(P[:, :128] @ W_dt + b_dt)   [2048 x 2048]
    gemm_tile<true><<<dim3(D_INNER / 64, M_ROWS / 64), 256, 0, stream>>>(
        P, NCAT, W_dt, D_INNER, delta, D_INNER, D_INNER, DT_RANK, b_dt);
    // 4) chunked scan: local -> fixup -> emit
    scan_pass1<<<dim3(D_INNER / 256, NC, SEQ_B), 256, 0, stream>>>(
        x, P, delta, A_log, chunkA, chunkH);
    scan_fixup<<<dim3((SEQ_B * D_INNER * D_STATE) / 256), 256, 0, stream>>>(chunkA, chunkH);
    scan_pass3<<<dim3(D_INNER / 256, NC, SEQ_B), 256, 0, stream>>>(
        x, P, delta, A_log, Dp, chunkH, y);
}

// Round 3
// 129.831 us; speedup vs baseline: 5.0269x; 2.1129x over previous
//
#include <hip/hip_runtime.h>
#include <math.h>

#define D_INNER 2048
#define DT_RANK 128
#define D_STATE 16
#define SEQ_B 2
#define SEQ_L 1024
#define M_ROWS (SEQ_B*SEQ_L)            // 2048
#define NCAT (DT_RANK + 2*D_STATE)      // 160
#define NC 32                           // scan chunks
#define LC (SEQ_L/NC)                   // 32 timesteps per chunk
#define KSPLIT 8                        // GEMM1 K-split
#define KCHUNK (D_INNER/KSPLIT)         // 256

// ---------------- concat W_delta|W_B|W_C -> Wcat [2048][160] ----------------
__global__ void concat_w(const float* __restrict__ Wd, const float* __restrict__ Wb,
                         const float* __restrict__ Wc, float* __restrict__ Wcat) {
    int i = blockIdx.x * 256 + threadIdx.x;
    if (i >= D_INNER * NCAT) return;
    int k = i / NCAT, j = i % NCAT;
    float v;
    if (j < DT_RANK)                 v = Wd[k * DT_RANK + j];
    else if (j < DT_RANK + D_STATE)  v = Wb[k * D_STATE + (j - DT_RANK)];
    else                             v = Wc[k * D_STATE + (j - DT_RANK - D_STATE)];
    Wcat[i] = v;
}

// ---------------- GEMM1 split-K: Ppart[z] += x[:, zK:(z+1)K] @ Wcat[zK:...] -
__global__ __launch_bounds__(256)
void gemm1_splitk(const float* __restrict__ A, const float* __restrict__ B,
                  float* __restrict__ Cpart)
{
    __shared__ __align__(16) float As[16][68];   // +4 pad: staging writes 2-way max
    __shared__ __align__(16) float Bs[16][64];
    const int tid = threadIdx.x;
    const int tx = tid & 15, ty = tid >> 4;
    const int row0 = blockIdx.y * 64;
    const int col0 = blockIdx.x * 64;
    const int kz   = blockIdx.z * KCHUNK;

    float acc[4][4] = {};

    for (int k0 = kz; k0 < kz + KCHUNK; k0 += 16) {
        #pragma unroll
        for (int p = 0; p < 4; ++p) {
            int m = (tid >> 4) + p * 16;
            int k = tid & 15;
            As[k][m] = A[(size_t)(row0 + m) * D_INNER + k0 + k];
        }
        #pragma unroll
        for (int p = 0; p < 4; ++p) {
            int k = (tid >> 6) + p * 4;
            int n = tid & 63;
            int col = col0 + n;
            Bs[k][n] = (col < NCAT) ? B[(size_t)(k0 + k) * NCAT + col] : 0.f;
        }
        __syncthreads();
        #pragma unroll
        for (int k = 0; k < 16; ++k) {
            float4 av = *(const float4*)&As[k][ty * 4];
            float4 bv = *(const float4*)&Bs[k][tx * 4];
            acc[0][0] += av.x * bv.x; acc[0][1] += av.x * bv.y; acc[0][2] += av.x * bv.z; acc[0][3] += av.x * bv.w;
            acc[1][0] += av.y * bv.x; acc[1][1] += av.y * bv.y; acc[1][2] += av.y * bv.z; acc[1][3] += av.y * bv.w;
            acc[2][0] += av.z * bv.x; acc[2][1] += av.z * bv.y; acc[2][2] += av.z * bv.z; acc[2][3] += av.z * bv.w;
            acc[3][0] += av.w * bv.x; acc[3][1] += av.w * bv.y; acc[3][2] += av.w * bv.z; acc[3][3] += av.w * bv.w;
        }
        __syncthreads();
    }

    float* Cp = Cpart + (size_t)blockIdx.z * M_ROWS * NCAT;
    #pragma unroll
    for (int i = 0; i < 4; ++i) {
        int row = row0 + ty * 4 + i;
        #pragma unroll
        for (int j = 0; j < 4; ++j) {
            int col = col0 + tx * 4 + j;
            if (col < NCAT) Cp[(size_t)row * NCAT + col] = acc[i][j];
        }
    }
}

// ---------------- reduce KSPLIT partials into P ----------------------------
__global__ __launch_bounds__(256)
void reduce_p(const float* __restrict__ Cpart, float* __restrict__ P) {
    int i = blockIdx.x * 256 + threadIdx.x;          // over M_ROWS*NCAT/4 float4s
    if (i >= M_ROWS * NCAT / 4) return;
    float4 s = ((const float4*)Cpart)[i];
    #pragma unroll
    for (int z = 1; z < KSPLIT; ++z) {
        float4 v = ((const float4*)(Cpart + (size_t)z * M_ROWS * NCAT))[i];
        s.x += v.x; s.y += v.y; s.z += v.z; s.w += v.w;
    }
    ((float4*)P)[i] = s;
}

// ---------------- GEMM2: delta = softplus(P[:, :128] @ W_dt + b_dt) --------
__global__ __launch_bounds__(256)
void gemm2_tile(const float* __restrict__ A, int lda,
                const float* __restrict__ B, int ldb,
                float* __restrict__ C, int ldc,
                int N, int K, const float* __restrict__ bias)
{
    __shared__ __align__(16) float As[16][68];
    __shared__ __align__(16) float Bs[16][64];
    const int tid = threadIdx.x;
    const int tx = tid & 15, ty = tid >> 4;
    const int row0 = blockIdx.y * 64;
    const int col0 = blockIdx.x * 64;

    float acc[4][4] = {};

    for (int k0 = 0; k0 < K; k0 += 16) {
        #pragma unroll
        for (int p = 0; p < 4; ++p) {
            int m = (tid >> 4) + p * 16;
            int k = tid & 15;
            As[k][m] = A[(size_t)(row0 + m) * lda + k0 + k];
        }
        #pragma unroll
        for (int p = 0; p < 4; ++p) {
            int k = (tid >> 6) + p * 4;
            int n = tid & 63;
            Bs[k][n] = B[(size_t)(k0 + k) * ldb + col0 + n];
        }
        __syncthreads();
        #pragma unroll
        for (int k = 0; k < 16; ++k) {
            float4 av = *(const float4*)&As[k][ty * 4];
            float4 bv = *(const float4*)&Bs[k][tx * 4];
            acc[0][0] += av.x * bv.x; acc[0][1] += av.x * bv.y; acc[0][2] += av.x * bv.z; acc[0][3] += av.x * bv.w;
            acc[1][0] += av.y * bv.x; acc[1][1] += av.y * bv.y; acc[1][2] += av.y * bv.z; acc[1][3] += av.y * bv.w;
            acc[2][0] += av.z * bv.x; acc[2][1] += av.z * bv.y; acc[2][2] += av.z * bv.z; acc[2][3] += av.z * bv.w;
            acc[3][0] += av.w * bv.x; acc[3][1] += av.w * bv.y; acc[3][2] += av.w * bv.z; acc[3][3] += av.w * bv.w;
        }
        __syncthreads();
    }

    #pragma unroll
    for (int i = 0; i < 4; ++i) {
        int row = row0 + ty * 4 + i;
        #pragma unroll
        for (int j = 0; j < 4; ++j) {
            int col = col0 + tx * 4 + j;
            float v = acc[i][j] + bias[col];
            v = (v > 20.f) ? v : log1pf(expf(v));
            C[(size_t)row * ldc + col] = v;
        }
    }
}

// ---------------- chunked scan: pass 1 (local scan, h0 = 0) ----------------
__global__ __launch_bounds__(256)
void scan_pass1(const float* __restrict__ x, const float* __restrict__ P,
                const float* __restrict__ delta, const float* __restrict__ A_log,
                float* __restrict__ chunkA, float* __restrict__ chunkH)
{
    const int d = blockIdx.x * 256 + threadIdx.x;
    const int c = blockIdx.y;
    const int b = blockIdx.z;
    const int t0 = c * LC;

    float Adn[D_STATE];
    #pragma unroll
    for (int n = 0; n < D_STATE; ++n) Adn[n] = -__expf(A_log[d * D_STATE + n]);

    float pA[D_STATE], h[D_STATE];
    #pragma unroll
    for (int n = 0; n < D_STATE; ++n) { pA[n] = 1.f; h[n] = 0.f; }

    const float* __restrict__ drow = delta + ((size_t)b * SEQ_L + t0) * D_INNER + d;
    const float* __restrict__ xrow = x     + ((size_t)b * SEQ_L + t0) * D_INNER + d;
    const float* __restrict__ prow = P     + ((size_t)b * SEQ_L + t0) * NCAT;

    for (int t = 0; t < LC; ++t) {
        float dt  = drow[(size_t)t * D_INNER];
        float xt  = xrow[(size_t)t * D_INNER];
        float dtx = dt * xt;
        const float4* Br = (const float4*)(prow + t * NCAT + DT_RANK);
        float4 b0 = Br[0], b1 = Br[1], b2 = Br[2], b3 = Br[3];
        float Bv[D_STATE] = {b0.x,b0.y,b0.z,b0.w, b1.x,b1.y,b1.z,b1.w,
                             b2.x,b2.y,b2.z,b2.w, b3.x,b3.y,b3.z,b3.w};
        #pragma unroll
        for (int n = 0; n < D_STATE; ++n) {
            float a = __expf(dt * Adn[n]);
            h[n]  = fmaf(a, h[n], dtx * Bv[n]);
            pA[n] *= a;
        }
    }
    size_t idx = (((size_t)b * D_INNER + d) * NC + c) * D_STATE;
    #pragma unroll
    for (int n = 0; n < D_STATE; ++n) { chunkA[idx + n] = pA[n]; chunkH[idx + n] = h[n]; }
}

// ---------------- pass 2: sequential fixup over NC chunks ------------------
__global__ __launch_bounds__(256)
void scan_fixup(const float* __restrict__ chunkA, float* __restrict__ chunkH)
{
    int g = blockIdx.x * 256 + threadIdx.x;           // B*D*16 = 65536
    int n = g & (D_STATE - 1);
    int d = (g >> 4) & (D_INNER - 1);
    int b = g >> 15;
    size_t base = ((size_t)b * D_INNER + d) * NC * D_STATE + n;
    float h = 0.f;
    for (int c = 0; c < NC; ++c) {
        size_t idx = base + (size_t)c * D_STATE;
        float a  = chunkA[idx];
        float hl = chunkH[idx];
        chunkH[idx] = h;                               // h0 for chunk c
        h = fmaf(a, h, hl);
    }
}

// ---------------- pass 3: re-run chunk from true h0, emit y ----------------
__global__ __launch_bounds__(256)
void scan_pass3(const float* __restrict__ x, const float* __restrict__ P,
                const float* __restrict__ delta, const float* __restrict__ A_log,
                const float* __restrict__ Dp, const float* __restrict__ chunkH,
                float* __restrict__ y)
{
    const int d = blockIdx.x * 256 + threadIdx.x;
    const int c = blockIdx.y;
    const int b = blockIdx.z;
    const int t0 = c * LC;

    float Adn[D_STATE];
    #pragma unroll
    for (int n = 0; n < D_STATE; ++n) Adn[n] = -__expf(A_log[d * D_STATE + n]);
    float Dd = Dp[d];

    float h[D_STATE];
    {
        size_t idx = (((size_t)b * D_INNER + d) * NC + c) * D_STATE;
        const float4* H = (const float4*)(chunkH + idx);
        float4 h0 = H[0], h1 = H[1], h2 = H[2], h3 = H[3];
        h[0]=h0.x; h[1]=h0.y; h[2]=h0.z; h[3]=h0.w;
        h[4]=h1.x; h[5]=h1.y; h[6]=h1.z; h[7]=h1.w;
        h[8]=h2.x; h[9]=h2.y; h[10]=h2.z; h[11]=h2.w;
        h[12]=h3.x; h[13]=h3.y; h[14]=h3.z; h[15]=h3.w;
    }

    const float* __restrict__ drow = delta + ((size_t)b * SEQ_L + t0) * D_INNER + d;
    const float* __restrict__ xrow = x     + ((size_t)b * SEQ_L + t0) * D_INNER + d;
    const float* __restrict__ prow = P     + ((size_t)b * SEQ_L + t0) * NCAT;
    float* __restrict__ yrow       = y     + ((size_t)b * SEQ_L + t0) * D_INNER + d;

    for (int t = 0; t < LC; ++t) {
        float dt  = drow[(size_t)t * D_INNER];
        float xt  = xrow[(size_t)t * D_INNER];
        float dtx = dt * xt;
        const float4* Br = (const float4*)(prow + t * NCAT + DT_RANK);
        float4 b0 = Br[0], b1 = Br[1], b2 = Br[2], b3 = Br[3];
        float Bv[D_STATE] = {b0.x,b0.y,b0.z,b0.w, b1.x,b1.y,b1.z,b1.w,
                             b2.x,b2.y,b2.z,b2.w, b3.x,b3.y,b3.z,b3.w};
        const float4* Cr = (const float4*)(prow + t * NCAT + DT_RANK + D_STATE);
        float4 c0 = Cr[0], c1 = Cr[1], c2 = Cr[2], c3 = Cr[3];
        float Cv[D_STATE] = {c0.x,c0.y,c0.z,c0.w, c1.x,c1.y,c1.z,c1.w,
                             c2.x,c2.y,c2.z,c2.w, c3.x,c3.y,c3.z,c3.w};
        float acc = xt * Dd;
        #pragma unroll
        for (int n = 0; n < D_STATE; ++n) {
            float a = __expf(dt * Adn[n]);
            h[n] = fmaf(a, h[n], dtx * Bv[n]);
            acc  = fmaf(h[n], Cv[n], acc);
        }
        yrow[(size_t)t * D_INNER] = acc;
    }
}

extern "C" void kernel_launch(void* const* d_in, const int* in_sizes, int n_in,
                              void* d_out, int out_size, void* d_ws, size_t ws_size,
                              hipStream_t stream) {
    const float* x       = (const float*)d_in[0];
    const float* W_delta = (const float*)d_in[1];
    const float* W_dt    = (const float*)d_in[2];
    const float* b_dt    = (const float*)d_in[3];
    const float* W_B     = (const float*)d_in[4];
    const float* W_C     = (const float*)d_in[5];
    const float* A_log   = (const float*)d_in[6];
    const float* Dp      = (const float*)d_in[7];
    float* y = (float*)d_out;

    char* ws = (char*)d_ws;
    float* Wcat   = (float*)(ws);                      // 1,310,720 B
    float* P      = (float*)(ws + 1310720);            // 1,310,720 B
    float* delta  = (float*)(ws + 2621440);            // 16,777,216 B
    // union region (temporally disjoint uses):
    //   Ppart: KSPLIT * 1,310,720 = 10,485,760 B   (GEMM1 + reduce)
    //   chunkA/chunkH: 2 x 8,388,608 B             (scan passes)
    float* Ppart  = (float*)(ws + 19398656);
    float* chunkA = (float*)(ws + 19398656);
    float* chunkH = (float*)(ws + 27787264);           // total ws use ~36.2 MB

    // 1) concat projection weights
    concat_w<<<dim3((D_INNER * NCAT + 255) / 256), 256, 0, stream>>>(W_delta, W_B, W_C, Wcat);
    // 2) P = x @ Wcat  via split-K partials + reduce
    gemm1_splitk<<<dim3(3, M_ROWS / 64, KSPLIT), 256, 0, stream>>>(x, Wcat, Ppart);
    reduce_p<<<dim3((M_ROWS * NCAT / 4 + 255) / 256), 256, 0, stream>>>(Ppart, P);
    // 3) delta = softplus(P[:, :128] @ W_dt + b_dt)   [2048 x 2048]
    gemm2_tile<<<dim3(D_INNER / 64, M_ROWS / 64), 256, 0, stream>>>(
        P, NCAT, W_dt, D_INNER, delta, D_INNER, D_INNER, DT_RANK, b_dt);
    // 4) chunked scan: local -> fixup -> emit
    scan_pass1<<<dim3(D_INNER / 256, NC, SEQ_B), 256, 0, stream>>>(
        x, P, delta, A_log, chunkA, chunkH);
    scan_fixup<<<dim3((SEQ_B * D_INNER * D_STATE) / 256), 256, 0, stream>>>(chunkA, chunkH);
    scan_pass3<<<dim3(D_INNER / 256, NC, SEQ_B), 256, 0, stream>>>(
        x, P, delta, A_log, Dp, chunkH, y);
}

// Round 6
// 100.537 us; speedup vs baseline: 6.4916x; 1.2914x over previous
//
#include <hip/hip_runtime.h>
#include <hip/hip_bf16.h>
#include <math.h>

#define D_INNER 2048
#define DT_RANK 128
#define D_STATE 16
#define SEQ_B 2
#define SEQ_L 1024
#define M_ROWS (SEQ_B*SEQ_L)            // 2048
#define NCAT (DT_RANK + 2*D_STATE)      // 160
#define NC 32                           // scan chunks
#define LC (SEQ_L/NC)                   // 32 timesteps per chunk
#define KS1 8                           // GEMM1 K-split
#define KC1 (D_INNER/KS1)               // 256
#define LDT 136                         // padded LDS row (bf16 elems): 272B stride, 16B aligned

typedef __attribute__((ext_vector_type(8))) short bf16x8;
typedef __attribute__((ext_vector_type(4))) float f32x4;

__device__ __forceinline__ unsigned short f2bf(float f) {
    __hip_bfloat16 h = __float2bfloat16(f);
    union { __hip_bfloat16 h; unsigned short u; } c; c.h = h; return c.u;
}

// ---------------- prep: WcatT bf16 [160][2048], W_dtT bf16 [2048][128] ------
__global__ __launch_bounds__(256) void prep_w(
    const float* __restrict__ Wd, const float* __restrict__ Wb,
    const float* __restrict__ Wc, const float* __restrict__ Wdt,
    unsigned short* __restrict__ WcatT, unsigned short* __restrict__ WdtT)
{
    int i = blockIdx.x * 256 + threadIdx.x;
    if (i < D_INNER * NCAT) {                 // coalesced reads, scattered 2B writes
        int k = i / NCAT, n = i % NCAT;
        float v;
        if (n < DT_RANK)                 v = Wd[k * DT_RANK + n];
        else if (n < DT_RANK + D_STATE)  v = Wb[k * D_STATE + (n - DT_RANK)];
        else                             v = Wc[k * D_STATE + (n - DT_RANK - D_STATE)];
        WcatT[(size_t)n * D_INNER + k] = f2bf(v);
    } else {
        int j = i - D_INNER * NCAT;           // W_dt is [128][2048]
        if (j < DT_RANK * D_INNER) {
            int k = j / D_INNER, n = j % D_INNER;
            WdtT[(size_t)n * DT_RANK + k] = f2bf(Wdt[j]);
        }
    }
}

// ---------------- x f32 -> bf16 --------------------------------------------
__global__ __launch_bounds__(256) void conv_x(const float* __restrict__ x,
                                              unsigned short* __restrict__ xb)
{
    int i = blockIdx.x * 256 + threadIdx.x;    // float4 index
    float4 v = ((const float4*)x)[i];
    ushort4 o; o.x = f2bf(v.x); o.y = f2bf(v.y); o.z = f2bf(v.z); o.w = f2bf(v.w);
    ((ushort4*)xb)[i] = o;
}

// ---------------- GEMM1 (MFMA, split-K): Ppart[z] = xb @ WcatT^T chunk ------
// tile 64M x 160N, K-chunk 256 staged as 2 x 128. 4 waves: 2x2 of 32x80.
// LDS: 17,408 + 43,520 = 60,928 B (< 64 KiB).
__global__ __launch_bounds__(256)
void gemm1_mfma(const unsigned short* __restrict__ xb,
                const unsigned short* __restrict__ WcatT,
                float* __restrict__ Ppart)
{
    __shared__ unsigned short As[64 * LDT];
    __shared__ unsigned short Bs[160 * LDT];
    const int tid = threadIdx.x;
    const int row0 = blockIdx.y * 64;
    const int kz = blockIdx.z * KC1;
    const int l = tid & 63, w = tid >> 6;
    const int wr = w >> 1, wc = w & 1;
    const int lr = l & 15, lh = l >> 4;

    f32x4 acc[2][5] = {};

    for (int ks = 0; ks < 2; ++ks) {
        const int k0 = kz + ks * 128;
        // A tile: 64 rows x 128 k = 1024 float4 loads (4 iters x 256 thr)
        #pragma unroll
        for (int i2 = 0; i2 < 4; ++i2) {
            int f = tid + i2 * 256; int r = f >> 4, c = f & 15;
            *(float4*)&As[r * LDT + c * 8] =
                *(const float4*)(xb + (size_t)(row0 + r) * D_INNER + k0 + c * 8);
        }
        // B tile: 160 rows x 128 k = 2560 float4 loads (10 iters x 256 thr)
        #pragma unroll
        for (int i2 = 0; i2 < 10; ++i2) {
            int f = tid + i2 * 256; int r = f >> 4, c = f & 15;
            *(float4*)&Bs[r * LDT + c * 8] =
                *(const float4*)(WcatT + (size_t)r * D_INNER + k0 + c * 8);
        }
        __syncthreads();
        #pragma unroll
        for (int kk = 0; kk < 4; ++kk) {
            bf16x8 a[2], b[5];
            #pragma unroll
            for (int m = 0; m < 2; ++m)
                a[m] = *(const bf16x8*)&As[(wr * 32 + m * 16 + lr) * LDT + kk * 32 + lh * 8];
            #pragma unroll
            for (int n = 0; n < 5; ++n)
                b[n] = *(const bf16x8*)&Bs[(wc * 80 + n * 16 + lr) * LDT + kk * 32 + lh * 8];
            #pragma unroll
            for (int m = 0; m < 2; ++m)
                #pragma unroll
                for (int n = 0; n < 5; ++n)
                    acc[m][n] = __builtin_amdgcn_mfma_f32_16x16x32_bf16(a[m], b[n], acc[m][n], 0, 0, 0);
        }
        __syncthreads();
    }

    float* Cp = Ppart + (size_t)blockIdx.z * M_ROWS * NCAT;
    #pragma unroll
    for (int m = 0; m < 2; ++m)
        #pragma unroll
        for (int n = 0; n < 5; ++n) {
            int col = wc * 80 + n * 16 + lr;
            #pragma unroll
            for (int r4 = 0; r4 < 4; ++r4) {
                int row = row0 + wr * 32 + m * 16 + lh * 4 + r4;
                Cp[(size_t)row * NCAT + col] = acc[m][n][r4];
            }
        }
}

// ---------------- reduce partials -> P f32, Plow bf16 ----------------------
__global__ __launch_bounds__(256)
void reduce_p(const float* __restrict__ Ppart, float* __restrict__ P,
              unsigned short* __restrict__ Plow)
{
    int i = blockIdx.x * 256 + threadIdx.x;    // float4 index over [2048][160]
    if (i >= M_ROWS * NCAT / 4) return;
    float4 s = ((const float4*)Ppart)[i];
    #pragma unroll
    for (int z = 1; z < KS1; ++z) {
        float4 v = ((const float4*)(Ppart + (size_t)z * M_ROWS * NCAT))[i];
        s.x += v.x; s.y += v.y; s.z += v.z; s.w += v.w;
    }
    ((float4*)P)[i] = s;
    int col4 = i % (NCAT / 4);
    if (col4 < DT_RANK / 4) {
        int row = i / (NCAT / 4);
        ushort4 o; o.x = f2bf(s.x); o.y = f2bf(s.y); o.z = f2bf(s.z); o.w = f2bf(s.w);
        ((ushort4*)Plow)[(size_t)row * (DT_RANK / 4) + col4] = o;
    }
}

// ---------------- GEMM2 (MFMA, one-shot K=128) + softplus ------------------
// tile 128M x 64N, 4 waves: 2x2 of 64x32. LDS: 34,816 + 17,408 = 52,224 B.
__global__ __launch_bounds__(256)
void gemm2_mfma(const unsigned short* __restrict__ Plow,
                const unsigned short* __restrict__ WdtT,
                const float* __restrict__ bias, float* __restrict__ delta)
{
    __shared__ unsigned short As[128 * LDT];
    __shared__ unsigned short Bs[64 * LDT];
    const int tid = threadIdx.x;
    const int row0 = blockIdx.y * 128, col0 = blockIdx.x * 64;
    const int l = tid & 63, w = tid >> 6;
    const int wr = w >> 1, wc = w & 1;
    const int lr = l & 15, lh = l >> 4;

    // A tile: 128 rows x 128 k = 2048 float4 loads (8 iters x 256 thr)
    #pragma unroll
    for (int i2 = 0; i2 < 8; ++i2) {
        int f = tid + i2 * 256; int r = f >> 4, c = f & 15;
        *(float4*)&As[r * LDT + c * 8] =
            *(const float4*)(Plow + (size_t)(row0 + r) * DT_RANK + c * 8);
    }
    // B tile: 64 rows x 128 k = 1024 float4 loads (4 iters x 256 thr)
    #pragma unroll
    for (int i2 = 0; i2 < 4; ++i2) {
        int f = tid + i2 * 256; int r = f >> 4, c = f & 15;
        *(float4*)&Bs[r * LDT + c * 8] =
            *(const float4*)(WdtT + (size_t)(col0 + r) * DT_RANK + c * 8);
    }
    __syncthreads();

    f32x4 acc[4][2] = {};
    #pragma unroll
    for (int kk = 0; kk < 4; ++kk) {
        bf16x8 a[4], b[2];
        #pragma unroll
        for (int m = 0; m < 4; ++m)
            a[m] = *(const bf16x8*)&As[(wr * 64 + m * 16 + lr) * LDT + kk * 32 + lh * 8];
        #pragma unroll
        for (int n = 0; n < 2; ++n)
            b[n] = *(const bf16x8*)&Bs[(wc * 32 + n * 16 + lr) * LDT + kk * 32 + lh * 8];
        #pragma unroll
        for (int m = 0; m < 4; ++m)
            #pragma unroll
            for (int n = 0; n < 2; ++n)
                acc[m][n] = __builtin_amdgcn_mfma_f32_16x16x32_bf16(a[m], b[n], acc[m][n], 0, 0, 0);
    }

    #pragma unroll
    for (int n = 0; n < 2; ++n) {
        int col = col0 + wc * 32 + n * 16 + lr;
        float bz = bias[col];
        #pragma unroll
        for (int m = 0; m < 4; ++m)
            #pragma unroll
            for (int r4 = 0; r4 < 4; ++r4) {
                int row = row0 + wr * 64 + m * 16 + lh * 4 + r4;
                float v = acc[m][n][r4] + bz;
                v = (v > 20.f) ? v : log1pf(expf(v));
                delta[(size_t)row * D_INNER + col] = v;
            }
    }
}

// ---------------- chunked scan: pass 1 (local scan, h0 = 0) ----------------
__global__ __launch_bounds__(256)
void scan_pass1(const float* __restrict__ x, const float* __restrict__ P,
                const float* __restrict__ delta, const float* __restrict__ A_log,
                float* __restrict__ chunkA, float* __restrict__ chunkH)
{
    const int d = blockIdx.x * 256 + threadIdx.x;
    const int c = blockIdx.y;
    const int b = blockIdx.z;
    const int t0 = c * LC;

    float Adn[D_STATE];
    #pragma unroll
    for (int n = 0; n < D_STATE; ++n) Adn[n] = -__expf(A_log[d * D_STATE + n]);

    float pA[D_STATE], h[D_STATE];
    #pragma unroll
    for (int n = 0; n < D_STATE; ++n) { pA[n] = 1.f; h[n] = 0.f; }

    const float* __restrict__ drow = delta + ((size_t)b * SEQ_L + t0) * D_INNER + d;
    const float* __restrict__ xrow = x     + ((size_t)b * SEQ_L + t0) * D_INNER + d;
    const float* __restrict__ prow = P     + ((size_t)b * SEQ_L + t0) * NCAT;

    for (int t = 0; t < LC; ++t) {
        float dt  = drow[(size_t)t * D_INNER];
        float xt  = xrow[(size_t)t * D_INNER];
        float dtx = dt * xt;
        const float4* Br = (const float4*)(prow + t * NCAT + DT_RANK);
        float4 b0 = Br[0], b1 = Br[1], b2 = Br[2], b3 = Br[3];
        float Bv[D_STATE] = {b0.x,b0.y,b0.z,b0.w, b1.x,b1.y,b1.z,b1.w,
                             b2.x,b2.y,b2.z,b2.w, b3.x,b3.y,b3.z,b3.w};
        #pragma unroll
        for (int n = 0; n < D_STATE; ++n) {
            float a = __expf(dt * Adn[n]);
            h[n]  = fmaf(a, h[n], dtx * Bv[n]);
            pA[n] *= a;
        }
    }
    size_t idx = (((size_t)b * D_INNER + d) * NC + c) * D_STATE;
    #pragma unroll
    for (int n = 0; n < D_STATE; ++n) { chunkA[idx + n] = pA[n]; chunkH[idx + n] = h[n]; }
}

// ---------------- pass 2: sequential fixup over NC chunks ------------------
__global__ __launch_bounds__(256)
void scan_fixup(const float* __restrict__ chunkA, float* __restrict__ chunkH)
{
    int g = blockIdx.x * 256 + threadIdx.x;           // B*D*16 = 65536
    int n = g & (D_STATE - 1);
    int d = (g >> 4) & (D_INNER - 1);
    int b = g >> 15;
    size_t base = ((size_t)b * D_INNER + d) * NC * D_STATE + n;
    float h = 0.f;
    for (int c = 0; c < NC; ++c) {
        size_t idx = base + (size_t)c * D_STATE;
        float a  = chunkA[idx];
        float hl = chunkH[idx];
        chunkH[idx] = h;                               // h0 for chunk c
        h = fmaf(a, h, hl);
    }
}

// ---------------- pass 3: re-run chunk from true h0, emit y ----------------
__global__ __launch_bounds__(256)
void scan_pass3(const float* __restrict__ x, const float* __restrict__ P,
                const float* __restrict__ delta, const float* __restrict__ A_log,
                const float* __restrict__ Dp, const float* __restrict__ chunkH,
                float* __restrict__ y)
{
    const int d = blockIdx.x * 256 + threadIdx.x;
    const int c = blockIdx.y;
    const int b = blockIdx.z;
    const int t0 = c * LC;

    float Adn[D_STATE];
    #pragma unroll
    for (int n = 0; n < D_STATE; ++n) Adn[n] = -__expf(A_log[d * D_STATE + n]);
    float Dd = Dp[d];

    float h[D_STATE];
    {
        size_t idx = (((size_t)b * D_INNER + d) * NC + c) * D_STATE;
        const float4* H = (const float4*)(chunkH + idx);
        float4 h0 = H[0], h1 = H[1], h2 = H[2], h3 = H[3];
        h[0]=h0.x; h[1]=h0.y; h[2]=h0.z; h[3]=h0.w;
        h[4]=h1.x; h[5]=h1.y; h[6]=h1.z; h[7]=h1.w;
        h[8]=h2.x; h[9]=h2.y; h[10]=h2.z; h[11]=h2.w;
        h[12]=h3.x; h[13]=h3.y; h[14]=h3.z; h[15]=h3.w;
    }

    const float* __restrict__ drow = delta + ((size_t)b * SEQ_L + t0) * D_INNER + d;
    const float* __restrict__ xrow = x     + ((size_t)b * SEQ_L + t0) * D_INNER + d;
    const float* __restrict__ prow = P     + ((size_t)b * SEQ_L + t0) * NCAT;
    float* __restrict__ yrow       = y     + ((size_t)b * SEQ_L + t0) * D_INNER + d;

    for (int t = 0; t < LC; ++t) {
        float dt  = drow[(size_t)t * D_INNER];
        float xt  = xrow[(size_t)t * D_INNER];
        float dtx = dt * xt;
        const float4* Br = (const float4*)(prow + t * NCAT + DT_RANK);
        float4 b0 = Br[0], b1 = Br[1], b2 = Br[2], b3 = Br[3];
        float Bv[D_STATE] = {b0.x,b0.y,b0.z,b0.w, b1.x,b1.y,b1.z,b1.w,
                             b2.x,b2.y,b2.z,b2.w, b3.x,b3.y,b3.z,b3.w};
        const float4* Cr = (const float4*)(prow + t * NCAT + DT_RANK + D_STATE);
        float4 c0 = Cr[0], c1 = Cr[1], c2 = Cr[2], c3 = Cr[3];
        float Cv[D_STATE] = {c0.x,c0.y,c0.z,c0.w, c1.x,c1.y,c1.z,c1.w,
                             c2.x,c2.y,c2.z,c2.w, c3.x,c3.y,c3.z,c3.w};
        float acc = xt * Dd;
        #pragma unroll
        for (int n = 0; n < D_STATE; ++n) {
            float a = __expf(dt * Adn[n]);
            h[n] = fmaf(a, h[n], dtx * Bv[n]);
            acc  = fmaf(h[n], Cv[n], acc);
        }
        yrow[(size_t)t * D_INNER] = acc;
    }
}

extern "C" void kernel_launch(void* const* d_in, const int* in_sizes, int n_in,
                              void* d_out, int out_size, void* d_ws, size_t ws_size,
                              hipStream_t stream) {
    const float* x       = (const float*)d_in[0];
    const float* W_delta = (const float*)d_in[1];
    const float* W_dt    = (const float*)d_in[2];
    const float* b_dt    = (const float*)d_in[3];
    const float* W_B     = (const float*)d_in[4];
    const float* W_C     = (const float*)d_in[5];
    const float* A_log   = (const float*)d_in[6];
    const float* Dp      = (const float*)d_in[7];
    float* y = (float*)d_out;

    char* ws = (char*)d_ws;
    // layout (16B-aligned offsets), total 36,569,088 B:
    unsigned short* WcatT = (unsigned short*)(ws);              //   655,360 B
    unsigned short* WdtT  = (unsigned short*)(ws + 655360);     //   524,288 B
    float*          P     = (float*)(ws + 1179648);             // 1,310,720 B
    unsigned short* Plow  = (unsigned short*)(ws + 2490368);    //   524,288 B
    // delta region 16,777,216 B; Ppart (10,485,760 B) aliases it — Ppart is
    // dead after reduce_p, delta written after by gemm2.
    float*          delta = (float*)(ws + 3014656);
    float*          Ppart = (float*)(ws + 3014656);
    // region R1: xb (gemm phase) / chunkA (scan phase) — 8,388,608 B each
    unsigned short* xb     = (unsigned short*)(ws + 19791872);
    float*          chunkA = (float*)(ws + 19791872);
    float*          chunkH = (float*)(ws + 28180480);           // 8,388,608 B

    // 1) weight prep (transpose + bf16)
    prep_w<<<dim3((D_INNER * NCAT + DT_RANK * D_INNER + 255) / 256), 256, 0, stream>>>(
        W_delta, W_B, W_C, W_dt, WcatT, WdtT);
    // 2) x -> bf16
    conv_x<<<dim3(M_ROWS * D_INNER / 4 / 256), 256, 0, stream>>>(x, xb);
    // 3) GEMM1: Ppart[z] = xb @ Wcat (chunk z), then reduce -> P f32 + Plow bf16
    gemm1_mfma<<<dim3(1, M_ROWS / 64, KS1), 256, 0, stream>>>(xb, WcatT, Ppart);
    reduce_p<<<dim3((M_ROWS * NCAT / 4 + 255) / 256), 256, 0, stream>>>(Ppart, P, Plow);
    // 4) GEMM2: delta = softplus(Plow @ W_dt + b_dt)
    gemm2_mfma<<<dim3(D_INNER / 64, M_ROWS / 128), 256, 0, stream>>>(Plow, WdtT, b_dt, delta);
    // 5) chunked scan: local -> fixup -> emit
    scan_pass1<<<dim3(D_INNER / 256, NC, SEQ_B), 256, 0, stream>>>(
        x, P, delta, A_log, chunkA, chunkH);
    scan_fixup<<<dim3((SEQ_B * D_INNER * D_STATE) / 256), 256, 0, stream>>>(chunkA, chunkH);
    scan_pass3<<<dim3(D_INNER / 256, NC, SEQ_B), 256, 0, stream>>>(
        x, P, delta, A_log, Dp, chunkH, y);
}